// Round 10
// baseline (633.852 us; speedup 1.0000x reference)
//
#include <hip/hip_runtime.h>
#include <hip/hip_bf16.h>

#define HEADS 8
#define NTOK 64
#define DIM 256

typedef __attribute__((ext_vector_type(8))) short bf16x8;
typedef __attribute__((ext_vector_type(4))) short bf16x4;
typedef __attribute__((ext_vector_type(4))) float f32x4;
typedef unsigned short u16;

__device__ __forceinline__ u16 f2bf(float f) {
    union { float f; unsigned u; } c; c.f = f;
    unsigned u = c.u;
    unsigned rounded = u + 0x7FFF + ((u >> 16) & 1);
    return (u16)(rounded >> 16);
}

// ---------------- prep: weights fp32->bf16, fused bias table ----------------
__global__ void prep_kernel(const float* __restrict__ wqkv,
                            const float* __restrict__ wproj,
                            const float* __restrict__ table,
                            const int* __restrict__ rel_index,
                            const float* __restrict__ mask,
                            u16* __restrict__ wq_bf,
                            u16* __restrict__ wp_bf,
                            float* __restrict__ bias) {
    const int NQ = 768 * 256;
    const int NP = 256 * 256;
    const int NB = HEADS * NTOK * NTOK;
    int total = NQ + NP + NB;
    for (int i = blockIdx.x * blockDim.x + threadIdx.x; i < total;
         i += gridDim.x * blockDim.x) {
        if (i < NQ) {
            wq_bf[i] = f2bf(wqkv[i]);
        } else if (i < NQ + NP) {
            wp_bf[i - NQ] = f2bf(wproj[i - NQ]);
        } else {
            int j = i - (NQ + NP);          // j = h*4096 + n*64 + m
            int h = j >> 12;
            int nm = j & 4095;
            bias[j] = table[rel_index[nm] * HEADS + h] + mask[j];
        }
    }
}

// ---------------- fused window attention (persistent) ----------------
// 256 blocks x 512 threads; each block owns one CU and loops over 16
// windows. x double-buffered in LDS (2 x 33.8 KB); window i+1's x is
// loaded to registers after barrier2 and ds_written after proj, hiding
// HBM latency under compute. Wave w = head w end-to-end; all-register
// attention (R6 structure). O overlays the current x buffer.
__launch_bounds__(512, 2)
__global__ void win_attn_kernel(const float* __restrict__ x,
                                const u16* __restrict__ wq_bf,
                                const u16* __restrict__ wp_bf,
                                const float* __restrict__ bias,
                                const float* __restrict__ b_proj,
                                float* __restrict__ out) {
    __shared__ u16 smem[33792];          // two 16896-u16 buffers
    const int bid = blockIdx.x;
    const int tid = threadIdx.x;
    const int w = tid >> 6;      // wave 0..7 == head
    const int l = tid & 63;
    const int l16 = l & 15;
    const int lhi = l >> 4;
    const int h = w;

    // loop-invariant weight row pointers
    const u16* rq0 = wq_bf + (h * 32 + l16) * 256;
    const u16* rq1 = rq0 + 16 * 256;
    const u16* rk0 = wq_bf + (256 + h * 32 + l16) * 256;
    const u16* rk1 = rk0 + 16 * 256;
    const u16* rv0 = wq_bf + (512 + h * 32 + l16) * 256;
    const u16* rv1 = rv0 + 16 * 256;
    const u16* prow0 = wp_bf + (w * 16 + l16) * 256;
    const u16* prow1 = wp_bf + ((w + 8) * 16 + l16) * 256;
    const float* biash = bias + h * 4096;

    const f32x4 zero = {0.f, 0.f, 0.f, 0.f};
    const float scale = 0.17677669529663687f;

    // ---- prologue: stage window bid*16 into buffer 0 ----
    {
        const float* xw = x + (size_t)(bid * 16) * (NTOK * DIM);
#pragma unroll
        for (int it = 0; it < 8; ++it) {
            int idx4 = tid + it * 512;
            float4 v = reinterpret_cast<const float4*>(xw)[idx4];
            int row = idx4 >> 6;
            int col = (idx4 & 63) * 4;
            ushort4 o;
            o.x = f2bf(v.x); o.y = f2bf(v.y); o.z = f2bf(v.z); o.w = f2bf(v.w);
            *reinterpret_cast<ushort4*>(&smem[row * 264 + col]) = o;
        }
    }
    __syncthreads();

    u16* cur = smem;
    u16* nxt = smem + 16896;

#pragma unroll 1
    for (int i = 0; i < 16; ++i) {
        const int win = bid * 16 + i;

        // ---- Phase 1: per-head QKV GEMM (reads cur) ----
        // Q,K swapped: D[dim][token] (lane l16 = token, reg = dim)
        // V normal:    D[token][dim] (lane l16 = dim,   reg = token)
        f32x4 qacc[2][4], kacc[2][4], vacc[4][2];
#pragma unroll
        for (int ct = 0; ct < 2; ++ct)
#pragma unroll
            for (int tt = 0; tt < 4; ++tt) {
                qacc[ct][tt] = zero; kacc[ct][tt] = zero; vacc[tt][ct] = zero;
            }

        // 2-deep weight prefetch: a* = ks, b* = ks+1
        bf16x8 aq0 = *reinterpret_cast<const bf16x8*>(rq0 + lhi * 8);
        bf16x8 aq1 = *reinterpret_cast<const bf16x8*>(rq1 + lhi * 8);
        bf16x8 ak0 = *reinterpret_cast<const bf16x8*>(rk0 + lhi * 8);
        bf16x8 ak1 = *reinterpret_cast<const bf16x8*>(rk1 + lhi * 8);
        bf16x8 av0 = *reinterpret_cast<const bf16x8*>(rv0 + lhi * 8);
        bf16x8 av1 = *reinterpret_cast<const bf16x8*>(rv1 + lhi * 8);
        bf16x8 bq0 = *reinterpret_cast<const bf16x8*>(rq0 + 32 + lhi * 8);
        bf16x8 bq1 = *reinterpret_cast<const bf16x8*>(rq1 + 32 + lhi * 8);
        bf16x8 bk0 = *reinterpret_cast<const bf16x8*>(rk0 + 32 + lhi * 8);
        bf16x8 bk1 = *reinterpret_cast<const bf16x8*>(rk1 + 32 + lhi * 8);
        bf16x8 bv0 = *reinterpret_cast<const bf16x8*>(rv0 + 32 + lhi * 8);
        bf16x8 bv1 = *reinterpret_cast<const bf16x8*>(rv1 + 32 + lhi * 8);

        for (int ks = 0; ks < 8; ++ks) {
            const int k0 = ks * 32 + lhi * 8;
            bf16x8 xf[4];
#pragma unroll
            for (int tt = 0; tt < 4; ++tt)
                xf[tt] = *reinterpret_cast<const bf16x8*>(&cur[(tt * 16 + l16) * 264 + k0]);
            bf16x8 nq0, nq1, nk0, nk1, nv0, nv1;
            if (ks < 6) {
                nq0 = *reinterpret_cast<const bf16x8*>(rq0 + k0 + 64);
                nq1 = *reinterpret_cast<const bf16x8*>(rq1 + k0 + 64);
                nk0 = *reinterpret_cast<const bf16x8*>(rk0 + k0 + 64);
                nk1 = *reinterpret_cast<const bf16x8*>(rk1 + k0 + 64);
                nv0 = *reinterpret_cast<const bf16x8*>(rv0 + k0 + 64);
                nv1 = *reinterpret_cast<const bf16x8*>(rv1 + k0 + 64);
            }
#pragma unroll
            for (int tt = 0; tt < 4; ++tt) {
                qacc[0][tt] = __builtin_amdgcn_mfma_f32_16x16x32_bf16(aq0, xf[tt], qacc[0][tt], 0, 0, 0);
                qacc[1][tt] = __builtin_amdgcn_mfma_f32_16x16x32_bf16(aq1, xf[tt], qacc[1][tt], 0, 0, 0);
                kacc[0][tt] = __builtin_amdgcn_mfma_f32_16x16x32_bf16(ak0, xf[tt], kacc[0][tt], 0, 0, 0);
                kacc[1][tt] = __builtin_amdgcn_mfma_f32_16x16x32_bf16(ak1, xf[tt], kacc[1][tt], 0, 0, 0);
                vacc[tt][0] = __builtin_amdgcn_mfma_f32_16x16x32_bf16(xf[tt], av0, vacc[tt][0], 0, 0, 0);
                vacc[tt][1] = __builtin_amdgcn_mfma_f32_16x16x32_bf16(xf[tt], av1, vacc[tt][1], 0, 0, 0);
            }
            aq0 = bq0; aq1 = bq1; ak0 = bk0; ak1 = bk1; av0 = bv0; av1 = bv1;
            bq0 = nq0; bq1 = nq1; bk0 = nk0; bk1 = nk1; bv0 = nv0; bv1 = nv1;
        }
        // all waves done reading x -> cur may be overwritten with O
        __syncthreads();

        // Pack accumulators -> 16x16x16 fragments (layout identities):
        //  qf/kf: lane=token(n/m), k-reg=dim      (A/B of S^T-MFMA)
        //  vf:    lane=dim d,      k-reg=token m  (A of PV-MFMA)
        bf16x4 qf[4][2], kf[4][2], vf[4][2];
#pragma unroll
        for (int tt = 0; tt < 4; ++tt)
#pragma unroll
            for (int ct = 0; ct < 2; ++ct) {
                bf16x4 q, k, v;
#pragma unroll
                for (int r = 0; r < 4; ++r) {
                    q[r] = (short)f2bf(qacc[ct][tt][r]);
                    k[r] = (short)f2bf(kacc[ct][tt][r]);
                    v[r] = (short)f2bf(vacc[tt][ct][r]);
                }
                qf[tt][ct] = q; kf[tt][ct] = k; vf[tt][ct] = v;
            }

        // ---- Phase 2: attention, fully in-register; O -> cur ----
        {
            f32x4 bias_c[4], bias_n[4];
#pragma unroll
            for (int mt = 0; mt < 4; ++mt)
                bias_c[mt] = *reinterpret_cast<const f32x4*>(
                    &biash[l16 * 64 + mt * 16 + lhi * 4]);

#pragma unroll
            for (int nt = 0; nt < 4; ++nt) {
                if (nt < 3) {
#pragma unroll
                    for (int mt = 0; mt < 4; ++mt)
                        bias_n[mt] = *reinterpret_cast<const f32x4*>(
                            &biash[((nt + 1) * 16 + l16) * 64 + mt * 16 + lhi * 4]);
                }
                // S^T = mfma(A=K, B=Q): lane l16 = n, (lhi,reg) = m
                f32x4 sacc[4];
#pragma unroll
                for (int mt = 0; mt < 4; ++mt) {
                    sacc[mt] = __builtin_amdgcn_mfma_f32_16x16x16bf16_1k(kf[mt][0], qf[nt][0], zero, 0, 0, 0);
                    sacc[mt] = __builtin_amdgcn_mfma_f32_16x16x16bf16_1k(kf[mt][1], qf[nt][1], sacc[mt], 0, 0, 0);
                }
                // softmax over m: 16 in-lane adds + 2 cross-lane shuffles
                float p[4][4];
                float sum = 0.f;
#pragma unroll
                for (int mt = 0; mt < 4; ++mt)
#pragma unroll
                    for (int r = 0; r < 4; ++r) {
                        // scores bounded -> exp without max-subtract
                        p[mt][r] = __expf(sacc[mt][r] * scale + bias_c[mt][r]);
                        sum += p[mt][r];
                    }
                sum += __shfl_xor(sum, 16, 64);
                sum += __shfl_xor(sum, 32, 64);
                float inv = 1.0f / sum;
                // P (unnormalized) is directly the PV B-frag: lane=n, k-reg=m
                bf16x4 pf[4];
#pragma unroll
                for (int mt = 0; mt < 4; ++mt) {
                    bf16x4 pk;
#pragma unroll
                    for (int r = 0; r < 4; ++r) pk[r] = (short)f2bf(p[mt][r]);
                    pf[mt] = pk;
                }
                // PV: O^T tile = sum_mt mfma(A=vf, B=pf): lane=n, reg=d
                f32x4 oa0 = zero, oa1 = zero;
#pragma unroll
                for (int mt = 0; mt < 4; ++mt) {
                    oa0 = __builtin_amdgcn_mfma_f32_16x16x16bf16_1k(vf[mt][0], pf[mt], oa0, 0, 0, 0);
                    oa1 = __builtin_amdgcn_mfma_f32_16x16x16bf16_1k(vf[mt][1], pf[mt], oa1, 0, 0, 0);
                }
                // O[n][d] packed writes into cur (inv lane-uniform)
                {
                    ushort4 o0, o1;
                    o0.x = f2bf(oa0[0] * inv); o0.y = f2bf(oa0[1] * inv);
                    o0.z = f2bf(oa0[2] * inv); o0.w = f2bf(oa0[3] * inv);
                    o1.x = f2bf(oa1[0] * inv); o1.y = f2bf(oa1[1] * inv);
                    o1.z = f2bf(oa1[2] * inv); o1.w = f2bf(oa1[3] * inv);
                    u16* orow = &cur[(nt * 16 + l16) * 264 + h * 32 + lhi * 4];
                    *reinterpret_cast<ushort4*>(orow) = o0;
                    *reinterpret_cast<ushort4*>(orow + 16) = o1;
                }
                if (nt < 3) {
#pragma unroll
                    for (int mt = 0; mt < 4; ++mt) bias_c[mt] = bias_n[mt];
                }
            }
        }
        __syncthreads();   // O visible block-wide; cur now holds O

        // ---- stage next window's x into registers (issue-early, T14) ----
        const bool have_next = (i < 15);
        float4 xs[8];
        if (have_next) {
            const float* xn = x + (size_t)(win + 1) * (NTOK * DIM);
#pragma unroll
            for (int it = 0; it < 8; ++it)
                xs[it] = reinterpret_cast<const float4*>(xn)[tid + it * 512];
        }

        // ---- Phase 3: proj GEMM (swapped): D[projcol][token] ----
        f32x4 acc3[2][4];
#pragma unroll
        for (int t = 0; t < 2; ++t)
#pragma unroll
            for (int tt = 0; tt < 4; ++tt) acc3[t][tt] = zero;

        bf16x8 wp0 = *reinterpret_cast<const bf16x8*>(prow0 + lhi * 8);
        bf16x8 wp1 = *reinterpret_cast<const bf16x8*>(prow1 + lhi * 8);
        for (int ks = 0; ks < 8; ++ks) {
            const int k0 = ks * 32 + lhi * 8;
            bf16x8 np0, np1;
            if (ks < 7) {
                np0 = *reinterpret_cast<const bf16x8*>(prow0 + k0 + 32);
                np1 = *reinterpret_cast<const bf16x8*>(prow1 + k0 + 32);
            }
#pragma unroll
            for (int tt = 0; tt < 4; ++tt) {
                bf16x8 of = *reinterpret_cast<const bf16x8*>(&cur[(tt * 16 + l16) * 264 + k0]);
                acc3[0][tt] = __builtin_amdgcn_mfma_f32_16x16x32_bf16(wp0, of, acc3[0][tt], 0, 0, 0);
                acc3[1][tt] = __builtin_amdgcn_mfma_f32_16x16x32_bf16(wp1, of, acc3[1][tt], 0, 0, 0);
            }
            wp0 = np0; wp1 = np1;
        }
        float* outw = out + (size_t)win * (NTOK * DIM);
#pragma unroll
        for (int t = 0; t < 2; ++t) {
            int colb = (w + t * 8) * 16 + lhi * 4;
            float4 bp = *reinterpret_cast<const float4*>(&b_proj[colb]);
#pragma unroll
            for (int tt = 0; tt < 4; ++tt) {
                float4 o;
                o.x = acc3[t][tt][0] + bp.x;
                o.y = acc3[t][tt][1] + bp.y;
                o.z = acc3[t][tt][2] + bp.z;
                o.w = acc3[t][tt][3] + bp.w;
                *reinterpret_cast<float4*>(&outw[(tt * 16 + l16) * 256 + colb]) = o;
            }
        }

        // ---- write staged x into nxt ----
        if (have_next) {
#pragma unroll
            for (int it = 0; it < 8; ++it) {
                int idx4 = tid + it * 512;
                int row = idx4 >> 6;
                int col = (idx4 & 63) * 4;
                ushort4 o;
                o.x = f2bf(xs[it].x); o.y = f2bf(xs[it].y);
                o.z = f2bf(xs[it].z); o.w = f2bf(xs[it].w);
                *reinterpret_cast<ushort4*>(&nxt[row * 264 + col]) = o;
            }
        }
        __syncthreads();   // nxt visible for next window's QKV
        u16* tmp = cur; cur = nxt; nxt = tmp;
    }
}

extern "C" void kernel_launch(void* const* d_in, const int* in_sizes, int n_in,
                              void* d_out, int out_size, void* d_ws, size_t ws_size,
                              hipStream_t stream) {
    const float* x     = (const float*)d_in[0];
    const float* mask  = (const float*)d_in[1];
    const float* wqkv  = (const float*)d_in[2];
    const float* wproj = (const float*)d_in[3];
    const float* bproj = (const float*)d_in[4];
    const float* table = (const float*)d_in[5];
    const int*   relix = (const int*)d_in[6];

    u16*   wq_bf = (u16*)d_ws;                 // 768*256 bf16
    u16*   wp_bf = wq_bf + 768 * 256;          // 256*256 bf16
    float* bias  = (float*)(wp_bf + 256 * 256); // 8*64*64 fp32

    prep_kernel<<<64, 512, 0, stream>>>(wqkv, wproj, table, relix, mask,
                                        wq_bf, wp_bf, bias);
    win_attn_kernel<<<256, 512, 0, stream>>>(x, wq_bf, wp_bf, bias, bproj,
                                             (float*)d_out);
}

// Round 12
// 385.111 us; speedup vs baseline: 1.6459x; 1.6459x over previous
//
#include <hip/hip_runtime.h>
#include <hip/hip_bf16.h>

#define HEADS 8
#define NTOK 64
#define DIM 256

typedef __attribute__((ext_vector_type(8))) short bf16x8;
typedef __attribute__((ext_vector_type(4))) short bf16x4;
typedef __attribute__((ext_vector_type(4))) float f32x4;
typedef unsigned short u16;

// native f32->bf16 (RTNE) — compiler lowers to v_cvt instructions and can
// pack adjacent pairs itself (m240: hand-written cvt_pk asm is SLOWER).
__device__ __forceinline__ u16 nf2bf(float f) {
    __hip_bfloat16 b = __float2bfloat16(f);
    return *reinterpret_cast<u16*>(&b);
}

// ---------------- prep: weights fp32->bf16, fused bias table ----------------
// bias is pre-multiplied by log2(e) so the kernel softmax uses exp2 directly.
__global__ void prep_kernel(const float* __restrict__ wqkv,
                            const float* __restrict__ wproj,
                            const float* __restrict__ table,
                            const int* __restrict__ rel_index,
                            const float* __restrict__ mask,
                            u16* __restrict__ wq_bf,
                            u16* __restrict__ wp_bf,
                            float* __restrict__ bias) {
    const int NQ = 768 * 256;
    const int NP = 256 * 256;
    const int NB = HEADS * NTOK * NTOK;
    int total = NQ + NP + NB;
    for (int i = blockIdx.x * blockDim.x + threadIdx.x; i < total;
         i += gridDim.x * blockDim.x) {
        if (i < NQ) {
            wq_bf[i] = nf2bf(wqkv[i]);
        } else if (i < NQ + NP) {
            wp_bf[i - NQ] = nf2bf(wproj[i - NQ]);
        } else {
            int j = i - (NQ + NP);          // j = h*4096 + n*64 + m
            int h = j >> 12;
            int nm = j & 4095;
            bias[j] = (table[rel_index[nm] * HEADS + h] + mask[j])
                      * 1.4426950408889634f;
        }
    }
}

// ---------------- fused window attention ----------------
// R6 structure (best verified: 386 us): 512 threads (8 waves), 1 window/
// block, wave w = head w end-to-end, all-register attention (S transposed ->
// in-register softmax; P,V raw accumulator layouts feed PV's MFMA directly).
// Two LDS buffers (x 33.8 KB + O 33.8 KB), 3 barriers. This round: native
// bf16 converts (compiler-packed) + exp2 softmax (log2e folded into bias).
__launch_bounds__(512, 2)
__global__ void win_attn_kernel(const float* __restrict__ x,
                                const u16* __restrict__ wq_bf,
                                const u16* __restrict__ wp_bf,
                                const float* __restrict__ bias,
                                const float* __restrict__ b_proj,
                                float* __restrict__ out) {
    __shared__ u16 smem[33792];          // 67,584 B
    u16* s_x = smem;                     // [64][264] x bf16
    u16* s_o = smem + 16896;             // [64][264] attention output O

    const int b = blockIdx.x;
    const int tid = threadIdx.x;
    const int w = tid >> 6;      // wave 0..7 == head
    const int l = tid & 63;
    const int l16 = l & 15;
    const int lhi = l >> 4;
    const int h = w;

    const u16* rq0 = wq_bf + (h * 32 + l16) * 256;
    const u16* rq1 = rq0 + 16 * 256;
    const u16* rk0 = wq_bf + (256 + h * 32 + l16) * 256;
    const u16* rk1 = rk0 + 16 * 256;
    const u16* rv0 = wq_bf + (512 + h * 32 + l16) * 256;
    const u16* rv1 = rv0 + 16 * 256;

    // 2-deep weight prefetch: a* = ks, b* = ks+1
    bf16x8 aq0 = *reinterpret_cast<const bf16x8*>(rq0 + lhi * 8);
    bf16x8 aq1 = *reinterpret_cast<const bf16x8*>(rq1 + lhi * 8);
    bf16x8 ak0 = *reinterpret_cast<const bf16x8*>(rk0 + lhi * 8);
    bf16x8 ak1 = *reinterpret_cast<const bf16x8*>(rk1 + lhi * 8);
    bf16x8 av0 = *reinterpret_cast<const bf16x8*>(rv0 + lhi * 8);
    bf16x8 av1 = *reinterpret_cast<const bf16x8*>(rv1 + lhi * 8);
    bf16x8 bq0 = *reinterpret_cast<const bf16x8*>(rq0 + 32 + lhi * 8);
    bf16x8 bq1 = *reinterpret_cast<const bf16x8*>(rq1 + 32 + lhi * 8);
    bf16x8 bk0 = *reinterpret_cast<const bf16x8*>(rk0 + 32 + lhi * 8);
    bf16x8 bk1 = *reinterpret_cast<const bf16x8*>(rk1 + 32 + lhi * 8);
    bf16x8 bv0 = *reinterpret_cast<const bf16x8*>(rv0 + 32 + lhi * 8);
    bf16x8 bv1 = *reinterpret_cast<const bf16x8*>(rv1 + 32 + lhi * 8);

    // ---- Phase 0: load x window -> bf16 LDS ----
    const float* xw = x + (size_t)b * (NTOK * DIM);
#pragma unroll
    for (int it = 0; it < 8; ++it) {
        int idx4 = tid + it * 512;                 // float4 index 0..4095
        float4 v = reinterpret_cast<const float4*>(xw)[idx4];
        int row = idx4 >> 6;
        int col = (idx4 & 63) * 4;
        ushort4 o;
        o.x = nf2bf(v.x); o.y = nf2bf(v.y); o.z = nf2bf(v.z); o.w = nf2bf(v.w);
        *reinterpret_cast<ushort4*>(&s_x[row * 264 + col]) = o;
    }
    __syncthreads();

    // ---- Phase 1: per-head QKV GEMM ----
    // Q,K swapped: D[dim][token] (lane l16 = token, reg = dim)
    // V normal:    D[token][dim] (lane l16 = dim,   reg = token)
    f32x4 qacc[2][4], kacc[2][4], vacc[4][2];
    const f32x4 zero = {0.f, 0.f, 0.f, 0.f};
#pragma unroll
    for (int ct = 0; ct < 2; ++ct)
#pragma unroll
        for (int tt = 0; tt < 4; ++tt) {
            qacc[ct][tt] = zero; kacc[ct][tt] = zero; vacc[tt][ct] = zero;
        }

    for (int ks = 0; ks < 8; ++ks) {
        const int k0 = ks * 32 + lhi * 8;
        bf16x8 xf[4];
#pragma unroll
        for (int tt = 0; tt < 4; ++tt)
            xf[tt] = *reinterpret_cast<const bf16x8*>(&s_x[(tt * 16 + l16) * 264 + k0]);
        bf16x8 nq0, nq1, nk0, nk1, nv0, nv1;
        if (ks < 6) {
            nq0 = *reinterpret_cast<const bf16x8*>(rq0 + k0 + 64);
            nq1 = *reinterpret_cast<const bf16x8*>(rq1 + k0 + 64);
            nk0 = *reinterpret_cast<const bf16x8*>(rk0 + k0 + 64);
            nk1 = *reinterpret_cast<const bf16x8*>(rk1 + k0 + 64);
            nv0 = *reinterpret_cast<const bf16x8*>(rv0 + k0 + 64);
            nv1 = *reinterpret_cast<const bf16x8*>(rv1 + k0 + 64);
        }
#pragma unroll
        for (int tt = 0; tt < 4; ++tt) {
            qacc[0][tt] = __builtin_amdgcn_mfma_f32_16x16x32_bf16(aq0, xf[tt], qacc[0][tt], 0, 0, 0);
            qacc[1][tt] = __builtin_amdgcn_mfma_f32_16x16x32_bf16(aq1, xf[tt], qacc[1][tt], 0, 0, 0);
            kacc[0][tt] = __builtin_amdgcn_mfma_f32_16x16x32_bf16(ak0, xf[tt], kacc[0][tt], 0, 0, 0);
            kacc[1][tt] = __builtin_amdgcn_mfma_f32_16x16x32_bf16(ak1, xf[tt], kacc[1][tt], 0, 0, 0);
            vacc[tt][0] = __builtin_amdgcn_mfma_f32_16x16x32_bf16(xf[tt], av0, vacc[tt][0], 0, 0, 0);
            vacc[tt][1] = __builtin_amdgcn_mfma_f32_16x16x32_bf16(xf[tt], av1, vacc[tt][1], 0, 0, 0);
        }
        aq0 = bq0; aq1 = bq1; ak0 = bk0; ak1 = bk1; av0 = bv0; av1 = bv1;
        bq0 = nq0; bq1 = nq1; bk0 = nk0; bk1 = nk1; bv0 = nv0; bv1 = nv1;
    }

    // Pack accumulators -> 16x16x16 fragments (layout identities):
    //  qf/kf: lane=token(n/m), k-reg=dim      (A/B of S^T-MFMA)
    //  vf:    lane=dim d,      k-reg=token m  (A of PV-MFMA)
    bf16x4 qf[4][2], kf[4][2], vf[4][2];
#pragma unroll
    for (int tt = 0; tt < 4; ++tt)
#pragma unroll
        for (int ct = 0; ct < 2; ++ct) {
            bf16x4 q, k, v;
#pragma unroll
            for (int r = 0; r < 4; ++r) {
                q[r] = (short)nf2bf(qacc[ct][tt][r]);
                k[r] = (short)nf2bf(kacc[ct][tt][r]);
                v[r] = (short)nf2bf(vacc[tt][ct][r]);
            }
            qf[tt][ct] = q; kf[tt][ct] = k; vf[tt][ct] = v;
        }

    // ---- Phase 2: attention, fully in-register; O -> s_o ----
    {
        // scale pre-multiplied by log2(e); bias table already is.
        const float scale = 0.17677669529663687f * 1.4426950408889634f;
        const float* biash = bias + h * 4096;
        f32x4 bias_c[4], bias_n[4];
#pragma unroll
        for (int mt = 0; mt < 4; ++mt)
            bias_c[mt] = *reinterpret_cast<const f32x4*>(
                &biash[l16 * 64 + mt * 16 + lhi * 4]);

#pragma unroll
        for (int nt = 0; nt < 4; ++nt) {
            if (nt < 3) {
#pragma unroll
                for (int mt = 0; mt < 4; ++mt)
                    bias_n[mt] = *reinterpret_cast<const f32x4*>(
                        &biash[((nt + 1) * 16 + l16) * 64 + mt * 16 + lhi * 4]);
            }
            // S^T = mfma(A=K, B=Q): lane l16 = n, (lhi,reg) = m
            f32x4 sacc[4];
#pragma unroll
            for (int mt = 0; mt < 4; ++mt) {
                sacc[mt] = __builtin_amdgcn_mfma_f32_16x16x16bf16_1k(kf[mt][0], qf[nt][0], zero, 0, 0, 0);
                sacc[mt] = __builtin_amdgcn_mfma_f32_16x16x16bf16_1k(kf[mt][1], qf[nt][1], sacc[mt], 0, 0, 0);
            }
            // softmax over m: exp2 (fma + v_exp), 16 in-lane adds + 2 shuffles
            float p[4][4];
            float sum = 0.f;
#pragma unroll
            for (int mt = 0; mt < 4; ++mt)
#pragma unroll
                for (int r = 0; r < 4; ++r) {
                    // scores bounded -> exp without max-subtract
                    p[mt][r] = exp2f(sacc[mt][r] * scale + bias_c[mt][r]);
                    sum += p[mt][r];
                }
            sum += __shfl_xor(sum, 16, 64);
            sum += __shfl_xor(sum, 32, 64);
            float inv = 1.0f / sum;
            // P (unnormalized) is directly the PV B-frag: lane=n, k-reg=m
            bf16x4 pf[4];
#pragma unroll
            for (int mt = 0; mt < 4; ++mt) {
                bf16x4 pk;
#pragma unroll
                for (int r = 0; r < 4; ++r) pk[r] = (short)nf2bf(p[mt][r]);
                pf[mt] = pk;
            }
            // PV: O^T tile = sum_mt mfma(A=vf, B=pf): lane=n, reg=d
            f32x4 oa0 = zero, oa1 = zero;
#pragma unroll
            for (int mt = 0; mt < 4; ++mt) {
                oa0 = __builtin_amdgcn_mfma_f32_16x16x16bf16_1k(vf[mt][0], pf[mt], oa0, 0, 0, 0);
                oa1 = __builtin_amdgcn_mfma_f32_16x16x16bf16_1k(vf[mt][1], pf[mt], oa1, 0, 0, 0);
            }
            // O[n][d] packed writes (inv is lane-uniform here)
            {
                ushort4 o0, o1;
                o0.x = nf2bf(oa0[0] * inv); o0.y = nf2bf(oa0[1] * inv);
                o0.z = nf2bf(oa0[2] * inv); o0.w = nf2bf(oa0[3] * inv);
                o1.x = nf2bf(oa1[0] * inv); o1.y = nf2bf(oa1[1] * inv);
                o1.z = nf2bf(oa1[2] * inv); o1.w = nf2bf(oa1[3] * inv);
                u16* orow = &s_o[(nt * 16 + l16) * 264 + h * 32 + lhi * 4];
                *reinterpret_cast<ushort4*>(orow) = o0;
                *reinterpret_cast<ushort4*>(orow + 16) = o1;
            }
            if (nt < 3) {
#pragma unroll
                for (int mt = 0; mt < 4; ++mt) bias_c[mt] = bias_n[mt];
            }
        }
    }
    __syncthreads();

    // ---- Phase 3: proj GEMM (swapped): D[projcol][token]; 2 tiles/wave ----
    f32x4 acc3[2][4];
#pragma unroll
    for (int t = 0; t < 2; ++t)
#pragma unroll
        for (int tt = 0; tt < 4; ++tt) acc3[t][tt] = zero;

    const u16* prow0 = wp_bf + (w * 16 + l16) * 256;
    const u16* prow1 = wp_bf + ((w + 8) * 16 + l16) * 256;
    bf16x8 wp0 = *reinterpret_cast<const bf16x8*>(prow0 + lhi * 8);
    bf16x8 wp1 = *reinterpret_cast<const bf16x8*>(prow1 + lhi * 8);
    for (int ks = 0; ks < 8; ++ks) {
        const int k0 = ks * 32 + lhi * 8;
        bf16x8 np0, np1;
        if (ks < 7) {
            np0 = *reinterpret_cast<const bf16x8*>(prow0 + k0 + 32);
            np1 = *reinterpret_cast<const bf16x8*>(prow1 + k0 + 32);
        }
#pragma unroll
        for (int tt = 0; tt < 4; ++tt) {
            bf16x8 of = *reinterpret_cast<const bf16x8*>(&s_o[(tt * 16 + l16) * 264 + k0]);
            acc3[0][tt] = __builtin_amdgcn_mfma_f32_16x16x32_bf16(wp0, of, acc3[0][tt], 0, 0, 0);
            acc3[1][tt] = __builtin_amdgcn_mfma_f32_16x16x32_bf16(wp1, of, acc3[1][tt], 0, 0, 0);
        }
        wp0 = np0; wp1 = np1;
    }
    float* outw = out + (size_t)b * (NTOK * DIM);
#pragma unroll
    for (int t = 0; t < 2; ++t) {
        int colb = (w + t * 8) * 16 + lhi * 4;
        float4 bp = *reinterpret_cast<const float4*>(&b_proj[colb]);
#pragma unroll
        for (int tt = 0; tt < 4; ++tt) {
            float4 o;
            o.x = acc3[t][tt][0] + bp.x;
            o.y = acc3[t][tt][1] + bp.y;
            o.z = acc3[t][tt][2] + bp.z;
            o.w = acc3[t][tt][3] + bp.w;
            *reinterpret_cast<float4*>(&outw[(tt * 16 + l16) * 256 + colb]) = o;
        }
    }
}

extern "C" void kernel_launch(void* const* d_in, const int* in_sizes, int n_in,
                              void* d_out, int out_size, void* d_ws, size_t ws_size,
                              hipStream_t stream) {
    const float* x     = (const float*)d_in[0];
    const float* mask  = (const float*)d_in[1];
    const float* wqkv  = (const float*)d_in[2];
    const float* wproj = (const float*)d_in[3];
    const float* bproj = (const float*)d_in[4];
    const float* table = (const float*)d_in[5];
    const int*   relix = (const int*)d_in[6];

    u16*   wq_bf = (u16*)d_ws;                 // 768*256 bf16
    u16*   wp_bf = wq_bf + 768 * 256;          // 256*256 bf16
    float* bias  = (float*)(wp_bf + 256 * 256); // 8*64*64 fp32 (pre-scaled)

    prep_kernel<<<64, 512, 0, stream>>>(wqkv, wproj, table, relix, mask,
                                        wq_bf, wp_bf, bias);
    win_attn_kernel<<<4096, 512, 0, stream>>>(x, wq_bf, wp_bf, bias, bproj,
                                              (float*)d_out);
}